// Round 3
// baseline (148.425 us; speedup 1.0000x reference)
//
#include <hip/hip_runtime.h>
#include <math.h>

// Problem constants (match reference).
#define T_TOTAL 131072
#define FEAT    8
#define HIDDEN  256
#define MAXK    10
#define BUF     50
#define RPB     64    // timesteps (output rows) per block
#define NT      256   // threads per block (4 waves)

// Native clang vector type: __builtin_nontemporal_store rejects the
// HIP_vector_type<float,4> wrapper class but accepts this.
typedef float floatx4 __attribute__((ext_vector_type(4)));

__device__ __forceinline__ float fit_loglog(const float Lk[MAXK]) {
    // log(1..10) as float32 constants (natural log, matches jnp.log).
    const float logk[MAXK] = {0.0f,        0.6931472f, 1.0986123f, 1.3862944f,
                              1.6094379f,  1.7917595f, 1.9459101f, 2.0794415f,
                              2.1972246f,  2.3025851f};
    float c = 0.f, sx = 0.f, sy = 0.f, sxy = 0.f, sxx = 0.f;
#pragma unroll
    for (int i = 0; i < MAXK; ++i) {
        if (Lk[i] > 0.0f) {
            const float lx = logk[i];
            const float ly = logf(Lk[i]);
            c   += 1.0f;
            sx  += lx;
            sy  += ly;
            sxy += ly * lx;
            sxx += lx * lx;
        }
    }
    float denom = c * sxx - sx * sx;
    denom = (denom != 0.0f) ? denom : 1.0f;
    const float slope = (c * sxy - sx * sy) / denom;
    return (c > 1.0f) ? -slope : 0.0f;
}

// R3 == R2 intent (single-variable A/B vs R1: NONTEMPORAL output stores),
// with the compile fix: ext_vector_type instead of HIP float4 for the NT
// builtin. Mechanism under test: the in-graph re-poison fill leaves L2/L3
// full of dirty poison lines; cached stores then allocate lines and force
// ~134 MB of poison writebacks, serializing the store stream (kernel ~62us
// vs its 21us write floor). NT stores bypass allocation -> direct HBM
// stream at ~6.7 TB/s.
__global__ __launch_bounds__(NT, 4) void hfd_fused(const float* __restrict__ x,
                                                   const float* __restrict__ w_lin,
                                                   const float* __restrict__ b_lin,
                                                   floatx4* __restrict__ outv) {
    __shared__ float sp[128];     // prices p[wbase-49 .. wbase+63], left pad zeroed
    __shared__ float shfd[RPB];   // the block's 64 hfd values

    const int tid   = threadIdx.x;
    const int lane  = tid & 63;
    const int wid   = tid >> 6;
    const int wbase = blockIdx.x * RPB;

    // Everyone loads their weight/bias column early (4 KB total, L2-hot).
    const floatx4 wv = ((const floatx4*)w_lin)[lane];
    const floatx4 bv = ((const floatx4*)b_lin)[lane];

    if (wid == 0) {
        // ---- stage prices: wave-private, no barrier needed before compute ----
        const int gt0 = wbase - (BUF - 1) + lane;
        sp[lane] = (gt0 >= 0) ? x[(size_t)gt0 * FEAT + 3] : 0.0f;
        if (lane < BUF - 1) {
            // gt0 + 64 = wbase + 15 + lane >= 15: always in-bounds.
            sp[64 + lane] = x[(size_t)(gt0 + 64) * FEAT + 3];
        }
        // (compiler inserts s_waitcnt lgkmcnt before the dependent ds_reads)

        const int t = wbase + lane;
        float hfd = 0.0f;

        if (t >= BUF - 1) {
            // -------- full window: nm1 = 49, compile-time constant --------
            float w[BUF];
#pragma unroll
            for (int q = 0; q < BUF; ++q) w[q] = sp[lane + q];

            float Lk[MAXK];
#pragma unroll
            for (int k = 1; k <= MAXK; ++k) {
                float acc = 0.0f;
#pragma unroll
                for (int m = 0; m < k; ++m) {
                    float S = 0.0f;
#pragma unroll
                    for (int q = m; q + k <= BUF - 1; q += k)
                        S += fabsf(w[q + k] - w[q]);
                    const int len = (BUF - 1 - m) / k + 1;   // always >= 2 here
                    acc += S * ((float)(BUF - 1) / (float)(len * k));  // folds
                }
                Lk[k - 1] = acc / (float)k;
            }
            hfd = fit_loglog(Lk);
        } else if (t >= MAXK) {
            // -------- partial window: t in [10,48] (block 0 only) --------
            const int   nm1  = t;
            const float nm1f = (float)nm1;
            const float* wp  = &sp[BUF - 1];   // wbase == 0 here; W[q] = p[q]

            float Lk[MAXK];
            for (int k = 1; k <= MAXK; ++k) {
                float acc = 0.0f;
                for (int m = 0; m < k; ++m) {
                    float S = 0.0f;
                    for (int q = m; q + k <= nm1; q += k)
                        S += fabsf(wp[q + k] - wp[q]);
                    const int length = (nm1 >= m) ? ((nm1 - m) / k + 1) : 0;
                    if (length >= 2)
                        acc += S * nm1f / (float)(length * k);
                }
                Lk[k - 1] = acc / (float)k;
            }
            hfd = fit_loglog(Lk);
        }
        // t < 10: hfd stays 0 (reference zeroes where n < MAX_K+1).

        shfd[lane] = hfd;
    }

    __syncthreads();

    // ---- block-cooperative store: 4 waves x 16 rows, row r = it*4 + wid ----
    float hv[16];
#pragma unroll
    for (int it = 0; it < 16; ++it) hv[it] = shfd[(it << 2) + wid];

#pragma unroll
    for (int it = 0; it < 16; ++it) {
        const float h = hv[it];
        floatx4 o;
        o.x = fmaxf(fmaf(h, wv.x, bv.x), 0.0f);
        o.y = fmaxf(fmaf(h, wv.y, bv.y), 0.0f);
        o.z = fmaxf(fmaf(h, wv.z, bv.z), 0.0f);
        o.w = fmaxf(fmaf(h, wv.w, bv.w), 0.0f);
        // NT store: bypass L2/L3 allocation (no dirty-poison eviction churn),
        // stream straight to HBM.
        __builtin_nontemporal_store(o, &outv[(size_t)(wbase + (it << 2) + wid) * (HIDDEN / 4) + lane]);
    }
}

extern "C" void kernel_launch(void* const* d_in, const int* in_sizes, int n_in,
                              void* d_out, int out_size, void* d_ws, size_t ws_size,
                              hipStream_t stream) {
    const float* x     = (const float*)d_in[0];
    const float* w_lin = (const float*)d_in[1];   // [HIDDEN,1] -> flat 256
    const float* b_lin = (const float*)d_in[2];   // [HIDDEN]
    floatx4* outv = (floatx4*)d_out;

    hfd_fused<<<dim3(T_TOTAL / RPB), dim3(NT), 0, stream>>>(x, w_lin, b_lin, outv);
}

// Round 4
// 141.780 us; speedup vs baseline: 1.0469x; 1.0469x over previous
//
#include <hip/hip_runtime.h>
#include <math.h>

// Problem constants (match reference).
#define T_TOTAL 131072
#define FEAT    8
#define HIDDEN  256
#define MAXK    10
#define BUF     50
#define RPB     64    // timesteps (output rows) per block
#define NT      256   // threads per block (4 waves)

__device__ __forceinline__ float fit_loglog(const float Lk[MAXK]) {
    // log(1..10) as float32 constants (natural log, matches jnp.log).
    const float logk[MAXK] = {0.0f,        0.6931472f, 1.0986123f, 1.3862944f,
                              1.6094379f,  1.7917595f, 1.9459101f, 2.0794415f,
                              2.1972246f,  2.3025851f};
    float c = 0.f, sx = 0.f, sy = 0.f, sxy = 0.f, sxx = 0.f;
#pragma unroll
    for (int i = 0; i < MAXK; ++i) {
        if (Lk[i] > 0.0f) {
            const float lx = logk[i];
            const float ly = logf(Lk[i]);
            c   += 1.0f;
            sx  += lx;
            sy  += ly;
            sxy += ly * lx;
            sxx += lx * lx;
        }
    }
    float denom = c * sxx - sx * sx;
    denom = (denom != 0.0f) ? denom : 1.0f;
    const float slope = (c * sxy - sx * sy) / denom;
    return (c > 1.0f) ? -slope : 0.0f;
}

// R4: R1 structure (cached stores — best at 142.0us; NT regressed to 148.4,
// refuting the poison-churn theory: output sits dirty in L3 and drains after
// kernel end). Single variable vs R1: s_setprio(1) wrapped around the wave-0
// HFD compute. Mechanism (T5 regime): wave 0's ~2400-cycle compute is the
// block critical path while 3 waves idle at the barrier and OTHER blocks'
// store waves contend for the same SIMD issue slots; raising the compute
// wave's priority shortens the block CP.
__global__ __launch_bounds__(NT, 4) void hfd_fused(const float* __restrict__ x,
                                                   const float* __restrict__ w_lin,
                                                   const float* __restrict__ b_lin,
                                                   float4* __restrict__ outv) {
    __shared__ float sp[128];     // prices p[wbase-49 .. wbase+63], left pad zeroed
    __shared__ float shfd[RPB];   // the block's 64 hfd values

    const int tid   = threadIdx.x;
    const int lane  = tid & 63;
    const int wid   = tid >> 6;
    const int wbase = blockIdx.x * RPB;

    // Everyone loads their weight/bias column early (4 KB total, L2-hot).
    const float4 wv = ((const float4*)w_lin)[lane];
    const float4 bv = ((const float4*)b_lin)[lane];

    if (wid == 0) {
        __builtin_amdgcn_s_setprio(1);   // compute wave is the block CP

        // ---- stage prices: wave-private, no barrier needed before compute ----
        const int gt0 = wbase - (BUF - 1) + lane;
        sp[lane] = (gt0 >= 0) ? x[(size_t)gt0 * FEAT + 3] : 0.0f;
        if (lane < BUF - 1) {
            // gt0 + 64 = wbase + 15 + lane >= 15: always in-bounds.
            sp[64 + lane] = x[(size_t)(gt0 + 64) * FEAT + 3];
        }
        // (compiler inserts s_waitcnt lgkmcnt before the dependent ds_reads)

        const int t = wbase + lane;
        float hfd = 0.0f;

        if (t >= BUF - 1) {
            // -------- full window: nm1 = 49, compile-time constant --------
            float w[BUF];
#pragma unroll
            for (int q = 0; q < BUF; ++q) w[q] = sp[lane + q];

            float Lk[MAXK];
#pragma unroll
            for (int k = 1; k <= MAXK; ++k) {
                float acc = 0.0f;
#pragma unroll
                for (int m = 0; m < k; ++m) {
                    float S = 0.0f;
#pragma unroll
                    for (int q = m; q + k <= BUF - 1; q += k)
                        S += fabsf(w[q + k] - w[q]);
                    const int len = (BUF - 1 - m) / k + 1;   // always >= 2 here
                    acc += S * ((float)(BUF - 1) / (float)(len * k));  // folds
                }
                Lk[k - 1] = acc / (float)k;
            }
            hfd = fit_loglog(Lk);
        } else if (t >= MAXK) {
            // -------- partial window: t in [10,48] (block 0 only) --------
            const int   nm1  = t;
            const float nm1f = (float)nm1;
            const float* wp  = &sp[BUF - 1];   // wbase == 0 here; W[q] = p[q]

            float Lk[MAXK];
            for (int k = 1; k <= MAXK; ++k) {
                float acc = 0.0f;
                for (int m = 0; m < k; ++m) {
                    float S = 0.0f;
                    for (int q = m; q + k <= nm1; q += k)
                        S += fabsf(wp[q + k] - wp[q]);
                    const int length = (nm1 >= m) ? ((nm1 - m) / k + 1) : 0;
                    if (length >= 2)
                        acc += S * nm1f / (float)(length * k);
                }
                Lk[k - 1] = acc / (float)k;
            }
            hfd = fit_loglog(Lk);
        }
        // t < 10: hfd stays 0 (reference zeroes where n < MAX_K+1).

        shfd[lane] = hfd;
        __builtin_amdgcn_s_setprio(0);
    }

    __syncthreads();

    // ---- block-cooperative store: 4 waves x 16 rows, row r = it*4 + wid ----
    float hv[16];
#pragma unroll
    for (int it = 0; it < 16; ++it) hv[it] = shfd[(it << 2) + wid];

#pragma unroll
    for (int it = 0; it < 16; ++it) {
        const float h = hv[it];
        float4 o;
        o.x = fmaxf(fmaf(h, wv.x, bv.x), 0.0f);
        o.y = fmaxf(fmaf(h, wv.y, bv.y), 0.0f);
        o.z = fmaxf(fmaf(h, wv.z, bv.z), 0.0f);
        o.w = fmaxf(fmaf(h, wv.w, bv.w), 0.0f);
        // Plain (cached) stores: output fits in L3, drains after kernel end;
        // NT stores forced the drain into kernel wall-clock (R3: +6.4us).
        outv[(size_t)(wbase + (it << 2) + wid) * (HIDDEN / 4) + lane] = o;
    }
}

extern "C" void kernel_launch(void* const* d_in, const int* in_sizes, int n_in,
                              void* d_out, int out_size, void* d_ws, size_t ws_size,
                              hipStream_t stream) {
    const float* x     = (const float*)d_in[0];
    const float* w_lin = (const float*)d_in[1];   // [HIDDEN,1] -> flat 256
    const float* b_lin = (const float*)d_in[2];   // [HIDDEN]
    float4* outv = (float4*)d_out;

    hfd_fused<<<dim3(T_TOTAL / RPB), dim3(NT), 0, stream>>>(x, w_lin, b_lin, outv);
}